// Round 2
// baseline (503.513 us; speedup 1.0000x reference)
//
#include <hip/hip_runtime.h>

// Elman RNN via MFMA — single-wave register-closed recurrence, ZERO barriers.
//   H^T_{t+1} = tanh(W_hh * H^T_t + W_ih * x_t^T + b),  out = sigmoid(fc_w.h_T + fc_b)
//
// mfma_f32_16x16x16f16 layouts (HW-verified in earlier round, absmax 3.9e-3):
//   A[m][k]: m = lane&15, k = quad*4 + i
//   B[k][n]: k = quad*4 + i, n = lane&15
//   D[m][n]: n = lane&15, m = quad*4 + reg
// => the packed D tile of m-tile mt IS the B-frag of k-tile kt=mt, in the SAME
//    lane. Previous version split the 4 m-tiles across 4 waves and paid an
//    LDS round-trip + __syncthreads per step; the barrier's implicit
//    s_waitcnt vmcnt(0) drained the x-prefetch ring every step (~450 cyc).
//    Here ONE WAVE owns all 4 m-tiles (full H=64 for its 16 samples), so the
//    recurrence closes entirely in registers: no LDS, no barrier, prefetch
//    stays in flight across steps.
//
// Per wave per step: 24 MFMAs (4 independent 6-deep chains, issue-interleaved
// 4-wide), 16 tanh (trans-pipe floor ~256 cyc/step), 4 pack4. 128 waves
// (one per sample-group of 16) as 128 single-wave blocks.

#define RN 2048
#define RT 512
#define RI 32
#define RH 64

typedef _Float16 h4 __attribute__((ext_vector_type(4)));
typedef float    f4 __attribute__((ext_vector_type(4)));

__device__ __forceinline__ int pk2(float a, float b) {
    return __builtin_bit_cast(int, __builtin_amdgcn_cvt_pkrtz(a, b));
}
__device__ __forceinline__ h4 pack4(float a, float b, float c, float d) {
    union { h4 v; int i[2]; } u;
    u.i[0] = pk2(a, b);
    u.i[1] = pk2(c, d);
    return u.v;
}
__device__ __forceinline__ h4 packf4(f4 v) { return pack4(v[0], v[1], v[2], v[3]); }

__device__ __forceinline__ float tanh_fast(float z) {
    // 1 - 2/(e^{2z}+1); exact saturation for large |z|
    float e = __expf(2.0f * z);
    return 1.0f - __fdividef(2.0f, e + 1.0f);
}

__global__ __launch_bounds__(64, 1) void rnn_mfma1(
    const float* __restrict__ x,
    const float* __restrict__ W_ih,
    const float* __restrict__ W_hh,
    const float* __restrict__ b_ih,
    const float* __restrict__ b_hh,
    const float* __restrict__ fc_w,
    const float* __restrict__ fc_b,
    float* __restrict__ out)
{
    const int lane = threadIdx.x & 63;
    const int col  = lane & 15;     // sample within group (n of B/D, m of A)
    const int quad = lane >> 4;     // 0..3
    const int g    = blockIdx.x;

    // ---- A-frags for ALL 4 m-tiles (W_hh: 32 VGPRs, W_ih: 16 VGPRs) ----
    h4 Ahh[4][4];
#pragma unroll
    for (int mt = 0; mt < 4; ++mt)
#pragma unroll
        for (int kt = 0; kt < 4; ++kt) {
            f4 v = *(const f4*)(W_hh + (mt * 16 + col) * RH + kt * 16 + quad * 4);
            Ahh[mt][kt] = packf4(v);
        }

    h4 Aih[4][2];
#pragma unroll
    for (int mt = 0; mt < 4; ++mt)
#pragma unroll
        for (int kt = 0; kt < 2; ++kt) {
            f4 v = *(const f4*)(W_ih + (mt * 16 + col) * RI + kt * 16 + quad * 4);
            Aih[mt][kt] = packf4(v);
        }

    f4 bias[4];
#pragma unroll
    for (int mt = 0; mt < 4; ++mt) {
        f4 bi = *(const f4*)(b_ih + mt * 16 + quad * 4);
        f4 bh = *(const f4*)(b_hh + mt * 16 + quad * 4);
        bias[mt] = bi + bh;
    }

    // ---- x stream for this lane's sample, 4-step static ring (stays in
    //      flight across steps — no barrier ever drains vmcnt) ----
    const float* xb = x + (size_t)(g * 16 + col) * (RT * RI);
    f4 xbuf[4][2];
#pragma unroll
    for (int s = 0; s < 4; ++s) {
        xbuf[s][0] = *(const f4*)(xb + s * RI + quad * 4);
        xbuf[s][1] = *(const f4*)(xb + s * RI + 16 + quad * 4);
    }

    // h0 = ones, already in B-frag layout
    h4 Bh[4];
#pragma unroll
    for (int kt = 0; kt < 4; ++kt) Bh[kt] = pack4(1.f, 1.f, 1.f, 1.f);
    f4 hv[4]; // f32 h of final step (all 4 m-tiles), for epilogue

    for (int t4 = 0; t4 < RT; t4 += 4) {
#pragma unroll
        for (int s = 0; s < 4; ++s) {
            const int t = t4 + s;
            h4 bx0 = packf4(xbuf[s][0]);
            h4 bx1 = packf4(xbuf[s][1]);
            int tn = t + 4; if (tn > RT - 1) tn = RT - 1;
            xbuf[s][0] = *(const f4*)(xb + tn * RI + quad * 4);
            xbuf[s][1] = *(const f4*)(xb + tn * RI + 16 + quad * 4);

            // x-part MFMAs are independent of Bh -> issue while previous
            // step's tanh/pack is still on the trans pipe.
            f4 c[4];
#pragma unroll
            for (int mt = 0; mt < 4; ++mt)
                c[mt] = __builtin_amdgcn_mfma_f32_16x16x16f16(Aih[mt][0], bx0, bias[mt], 0, 0, 0);
#pragma unroll
            for (int mt = 0; mt < 4; ++mt)
                c[mt] = __builtin_amdgcn_mfma_f32_16x16x16f16(Aih[mt][1], bx1, c[mt], 0, 0, 0);

            // hh part: kt outer / mt inner -> each chain sees 4-MFMA issue
            // gaps, hiding dependent-MFMA latency.
#pragma unroll
            for (int kt = 0; kt < 4; ++kt)
#pragma unroll
                for (int mt = 0; mt < 4; ++mt)
                    c[mt] = __builtin_amdgcn_mfma_f32_16x16x16f16(Ahh[mt][kt], Bh[kt], c[mt], 0, 0, 0);

            // tanh + pack: D tile mt, packed, IS next step's B-frag kt=mt.
#pragma unroll
            for (int mt = 0; mt < 4; ++mt) {
                hv[mt][0] = tanh_fast(c[mt][0]);
                hv[mt][1] = tanh_fast(c[mt][1]);
                hv[mt][2] = tanh_fast(c[mt][2]);
                hv[mt][3] = tanh_fast(c[mt][3]);
                Bh[mt] = packf4(hv[mt]);
            }
        }
    }

    // ---- epilogue: out[n] = sigmoid(sum_j fc_w[j] h[n][j] + fc_b) ----
    // lane (quad,col) holds h[col][j] for j = mt*16 + quad*4 + r  (16 j's)
    {
        float s = 0.f;
#pragma unroll
        for (int mt = 0; mt < 4; ++mt) {
            f4 wv = *(const f4*)(fc_w + mt * 16 + quad * 4);
            s += wv[0] * hv[mt][0] + wv[1] * hv[mt][1]
               + wv[2] * hv[mt][2] + wv[3] * hv[mt][3];
        }
        s += __shfl_xor(s, 16, 64);
        s += __shfl_xor(s, 32, 64); // sum over the 4 quads -> full 64-unit dot
        if (quad == 0) {
            float logit = s + fc_b[0];
            out[g * 16 + col] = __fdividef(1.0f, 1.0f + __expf(-logit));
        }
    }
}

extern "C" void kernel_launch(void* const* d_in, const int* in_sizes, int n_in,
                              void* d_out, int out_size, void* d_ws, size_t ws_size,
                              hipStream_t stream) {
    rnn_mfma1<<<RN / 16, 64, 0, stream>>>(
        (const float*)d_in[0], (const float*)d_in[1], (const float*)d_in[2],
        (const float*)d_in[3], (const float*)d_in[4], (const float*)d_in[5],
        (const float*)d_in[6], (float*)d_out);
}

// Round 3
// 307.366 us; speedup vs baseline: 1.6382x; 1.6382x over previous
//
#include <hip/hip_runtime.h>

// Elman RNN via MFMA, register-chained recurrence, j-split across 4 waves.
//   H^T_{t+1} = tanh(W_hh * H^T_t + W_ih * x_t^T + b),  out = sigmoid(fc_w.h_T + fc_b)
//
// mfma_f32_16x16x16f16 layouts (HW-verified, absmax 3.9e-3):
//   A[m][k]: m = lane&15, k = quad*4 + i
//   B[k][n]: k = quad*4 + i, n = lane&15
//   D[m][n]: n = lane&15, m = quad*4 + reg
// => a wave's packed D tile (m-tile w) IS the B-frag of k-tile kt=w for the
//    next step, in the same lane. Waves exchange B-frags through LDS.
//
// KEY CHANGE vs the 167us baseline: the per-step __syncthreads() is replaced
// by raw `s_waitcnt lgkmcnt(0); s_barrier` (inline asm, memory-clobbered).
// __syncthreads() lowers with an implicit s_waitcnt vmcnt(0) that drained the
// 4-step x-prefetch ring EVERY step (~300-400 cy of exposed load latency);
// the raw barrier waits only on the LDS write, so global loads stay in
// flight across steps (counted-vmcnt discipline, HK/m201 pattern).
// Race safety: hb is double-buffered (p = t&1); a wave can only overwrite
// buffer p at step t+2, after the barrier of step t+1, by which time every
// wave has consumed step t's reads (they feed MFMAs issued before that
// barrier). Single-wave variant (register-closed, no barrier) was measured
// 361us: zero latency hiding at 1 wave/SIMD — reverted.
//
// Micro-opts: own k-tile B-frag taken from the local pack (3 ds_reads, not
// 4); A-frags loaded in wave-rotated kt order (kt=(w+i)&3, rotation in the
// LOAD ADDRESS so all register-array indices stay static) so the hh chain
// consumes the own-tile frag first, giving ds_reads more time to land.

#define RN 2048
#define RT 512
#define RI 32
#define RH 64

typedef _Float16 h4 __attribute__((ext_vector_type(4)));
typedef float    f4 __attribute__((ext_vector_type(4)));

__device__ __forceinline__ int pk2(float a, float b) {
    return __builtin_bit_cast(int, __builtin_amdgcn_cvt_pkrtz(a, b));
}
__device__ __forceinline__ h4 pack4(float a, float b, float c, float d) {
    union { h4 v; int i[2]; } u;
    u.i[0] = pk2(a, b);
    u.i[1] = pk2(c, d);
    return u.v;
}
__device__ __forceinline__ h4 packf4(f4 v) { return pack4(v[0], v[1], v[2], v[3]); }

__device__ __forceinline__ float tanh_fast(float z) {
    // 1 - 2/(e^{2z}+1); exact saturation for large |z|
    float e = __expf(2.0f * z);
    return 1.0f - __fdividef(2.0f, e + 1.0f);
}

__global__ __launch_bounds__(256, 1) void rnn_mfma4(
    const float* __restrict__ x,
    const float* __restrict__ W_ih,
    const float* __restrict__ W_hh,
    const float* __restrict__ b_ih,
    const float* __restrict__ b_hh,
    const float* __restrict__ fc_w,
    const float* __restrict__ fc_b,
    float* __restrict__ out)
{
    const int tid  = threadIdx.x;
    const int w    = tid >> 6;      // wave id = m-tile
    const int lane = tid & 63;
    const int col  = lane & 15;     // sample within group
    const int quad = lane >> 4;     // 0..3
    const int g    = blockIdx.x;

    // h exchange: [buf][kt*64 + lane] -> 8B B-frag. 2-way bank alias only.
    __shared__ unsigned long long hb[2][4 * 64];
    __shared__ float ob[4][16];

    // ---- A-frags for my m-tile, kt ROTATED: slot i holds kt=(w+i)&3 ----
    h4 Ahh[4];
#pragma unroll
    for (int i = 0; i < 4; ++i) {
        const int kt = (w + i) & 3;
        f4 v = *(const f4*)(W_hh + (w * 16 + col) * RH + kt * 16 + quad * 4);
        Ahh[i] = packf4(v);
    }
    h4 Aih[2];
#pragma unroll
    for (int kt = 0; kt < 2; ++kt) {
        f4 v = *(const f4*)(W_ih + (w * 16 + col) * RI + kt * 16 + quad * 4);
        Aih[kt] = packf4(v);
    }
    f4 biasv;
    {
        f4 bi = *(const f4*)(b_ih + w * 16 + quad * 4);
        f4 bh = *(const f4*)(b_hh + w * 16 + quad * 4);
        biasv = bi + bh;
    }

    // ---- x stream for this lane's sample, 4-step static ring ----
    const float* xb = x + (size_t)(g * 16 + col) * (RT * RI);
    f4 xbuf[4][2];
#pragma unroll
    for (int s = 0; s < 4; ++s) {
        xbuf[s][0] = *(const f4*)(xb + s * RI + quad * 4);
        xbuf[s][1] = *(const f4*)(xb + s * RI + 16 + quad * 4);
    }

    // h0 = ones, already in B-frag layout. Bh[i] corresponds to kt=(w+i)&3;
    // Bh[0] is my OWN tile (comes from my local pack, never from LDS).
    h4 Bh[4];
#pragma unroll
    for (int i = 0; i < 4; ++i) Bh[i] = pack4(1.f, 1.f, 1.f, 1.f);
    f4 hv; // f32 h of final step (my m-tile rows), for epilogue

    // LDS byte addresses for the 3 foreign ds_reads (kt = (w+1..3)&3)
    for (int t4 = 0; t4 < RT; t4 += 4) {
#pragma unroll
        for (int s = 0; s < 4; ++s) {
            const int t = t4 + s;
            h4 bx0 = packf4(xbuf[s][0]);
            h4 bx1 = packf4(xbuf[s][1]);
            int tn = t + 4; if (tn > RT - 1) tn = RT - 1;
            xbuf[s][0] = *(const f4*)(xb + tn * RI + quad * 4);
            xbuf[s][1] = *(const f4*)(xb + tn * RI + 16 + quad * 4);

            // two balanced 3-deep MFMA chains; x-part is independent of Bh,
            // so it issues while the ds_reads of h are still in flight.
            f4 c0 = __builtin_amdgcn_mfma_f32_16x16x16f16(Aih[0], bx0, biasv, 0, 0, 0);
            f4 c1 = __builtin_amdgcn_mfma_f32_16x16x16f16(Aih[1], bx1, f4{0.f, 0.f, 0.f, 0.f}, 0, 0, 0);
            // own-tile frag (Bh[0]) first: no LDS dependency at all.
            c0 = __builtin_amdgcn_mfma_f32_16x16x16f16(Ahh[0], Bh[0], c0, 0, 0, 0);
            c1 = __builtin_amdgcn_mfma_f32_16x16x16f16(Ahh[1], Bh[1], c1, 0, 0, 0);
            c0 = __builtin_amdgcn_mfma_f32_16x16x16f16(Ahh[2], Bh[2], c0, 0, 0, 0);
            c1 = __builtin_amdgcn_mfma_f32_16x16x16f16(Ahh[3], Bh[3], c1, 0, 0, 0);
            f4 acc = c0 + c1;

            hv[0] = tanh_fast(acc[0]);
            hv[1] = tanh_fast(acc[1]);
            hv[2] = tanh_fast(acc[2]);
            hv[3] = tanh_fast(acc[3]);

            // publish my D tile as next step's B-frag kt = w
            const int p = t & 1;
            h4 hpk = packf4(hv);
            hb[p][w * 64 + lane] = __builtin_bit_cast(unsigned long long, hpk);
            // RAW BARRIER: wait only on the LDS write (lgkmcnt), NOT on the
            // global x-prefetch (vmcnt) — loads stay in flight across steps.
            asm volatile("s_waitcnt lgkmcnt(0)\n\ts_barrier" ::: "memory");
            Bh[0] = hpk; // own tile, no LDS round-trip
            Bh[1] = __builtin_bit_cast(h4, hb[p][(((w + 1) & 3)) * 64 + lane]);
            Bh[2] = __builtin_bit_cast(h4, hb[p][(((w + 2) & 3)) * 64 + lane]);
            Bh[3] = __builtin_bit_cast(h4, hb[p][(((w + 3) & 3)) * 64 + lane]);
        }
    }

    // ---- epilogue: out[n] = sigmoid(sum_j fc_w[j] h[n][j] + fc_b) ----
    {
        f4 wv = *(const f4*)(fc_w + w * 16 + quad * 4);
        float s = wv[0] * hv[0] + wv[1] * hv[1] + wv[2] * hv[2] + wv[3] * hv[3];
        s += __shfl_xor(s, 16, 64);
        s += __shfl_xor(s, 32, 64); // all lanes: partial over my 16 hidden units
        if (quad == 0) ob[w][col] = s;
        __syncthreads();
        if (w == 0 && lane < 16) {
            float logit = ob[0][lane] + ob[1][lane] + ob[2][lane] + ob[3][lane] + fc_b[0];
            out[g * 16 + lane] = __fdividef(1.0f, 1.0f + __expf(-logit));
        }
    }
}

extern "C" void kernel_launch(void* const* d_in, const int* in_sizes, int n_in,
                              void* d_out, int out_size, void* d_ws, size_t ws_size,
                              hipStream_t stream) {
    rnn_mfma4<<<RN / 16, 256, 0, stream>>>(
        (const float*)d_in[0], (const float*)d_in[1], (const float*)d_in[2],
        (const float*)d_in[3], (const float*)d_in[4], (const float*)d_in[5],
        (const float*)d_in[6], (float*)d_out);
}